// Round 5
// baseline (115.721 us; speedup 1.0000x reference)
//
#include <hip/hip_runtime.h>

// QSP via Laurent polynomial: u00(theta) = sum_{m odd, |m|<=127} gamma_m e^{i m theta}
// R5: setup is ONE WAVE (64 threads), coefficients held in registers (4 slots/lane),
// neighbor exchange via __shfl_up/__shfl_down -> zero barriers, zero LDS state.
// Main: Horner in z = e^{2 i theta}, uniform coefficient loads, 4 elements/thread.
//
// Validated recurrence (R2-R4): power index i = m+127 in [0,254],
//   A'[i] = e_k  * 0.5*(A[i-1]+A[i+1]+B[i-1]-B[i+1])
//   B'[i] = e_k^** 0.5*(A[i-1]-A[i+1]+B[i-1]+B[i+1])
// Init A[127] = e_0, B = 0. gamma_t = A_final[2t], t=0..127.

typedef float v2f __attribute__((ext_vector_type(2)));

#define NPHI 128

__global__ __launch_bounds__(64) void qsp_setup(
    const float* __restrict__ phis,
    float4* __restrict__ tab)       // 128 entries: {gr, gr, gi, gi}
{
    __shared__ float2 e[NPHI];
    const int L = threadIdx.x;      // 0..63, single wave

    {
        float sp, cp;
        __sincosf(phis[L], &sp, &cp);
        e[L] = make_float2(cp, sp);
        __sincosf(phis[L + 64], &sp, &cp);
        e[L + 64] = make_float2(cp, sp);
    }
    __syncthreads();  // single wave: compiles to waitcnt only

    // lane L holds slots s=0..3 <-> i = 4L+s (i=255 is a guard, provably stays 0)
    float Ar[4] = {0,0,0,0}, Ai[4] = {0,0,0,0};
    float Br[4] = {0,0,0,0}, Bi[4] = {0,0,0,0};

    const float2 e0 = e[0];
    if (L == 31) { Ar[3] = e0.x; Ai[3] = e0.y; }   // i = 127 = 4*31+3

    for (int k = 1; k < NPHI; ++k) {
        const float2 ek = e[k];
        // cross-lane neighbors
        float uAr = __shfl_up(Ar[3], 1, 64), uAi = __shfl_up(Ai[3], 1, 64);
        float uBr = __shfl_up(Br[3], 1, 64), uBi = __shfl_up(Bi[3], 1, 64);
        float dAr = __shfl_down(Ar[0], 1, 64), dAi = __shfl_down(Ai[0], 1, 64);
        float dBr = __shfl_down(Br[0], 1, 64), dBi = __shfl_down(Bi[0], 1, 64);
        if (L == 0)  { uAr = 0.f; uAi = 0.f; uBr = 0.f; uBi = 0.f; }
        if (L == 63) { dAr = 0.f; dAi = 0.f; dBr = 0.f; dBi = 0.f; }

        float nAr[4], nAi[4], nBr[4], nBi[4];
        #pragma unroll
        for (int s = 0; s < 4; ++s) {
            const float Amr = (s == 0) ? uAr : Ar[s-1];
            const float Ami = (s == 0) ? uAi : Ai[s-1];
            const float Bmr = (s == 0) ? uBr : Br[s-1];
            const float Bmi = (s == 0) ? uBi : Bi[s-1];
            const float Apr = (s == 3) ? dAr : Ar[s+1];
            const float Api = (s == 3) ? dAi : Ai[s+1];
            const float Bpr = (s == 3) ? dBr : Br[s+1];
            const float Bpi = (s == 3) ? dBi : Bi[s+1];
            const float sAr = 0.5f * (Amr + Apr + Bmr - Bpr);
            const float sAi = 0.5f * (Ami + Api + Bmi - Bpi);
            const float sBr = 0.5f * (Amr - Apr + Bmr + Bpr);
            const float sBi = 0.5f * (Ami - Api + Bmi + Bpi);
            nAr[s] = ek.x * sAr - ek.y * sAi;
            nAi[s] = ek.x * sAi + ek.y * sAr;
            nBr[s] = ek.x * sBr + ek.y * sBi;
            nBi[s] = ek.x * sBi - ek.y * sBr;
        }
        #pragma unroll
        for (int s = 0; s < 4; ++s) {
            Ar[s] = nAr[s]; Ai[s] = nAi[s];
            Br[s] = nBr[s]; Bi[s] = nBi[s];
        }
    }

    // gamma_t = A[i=2t]: lane L -> t=2L (slot 0), t=2L+1 (slot 2)
    tab[2*L]     = make_float4(Ar[0], Ar[0], Ai[0], Ai[0]);
    tab[2*L + 1] = make_float4(Ar[2], Ar[2], Ai[2], Ai[2]);
}

__global__ __launch_bounds__(256) void qsp_main(
    const float* __restrict__ th,
    const float4* __restrict__ tab,   // uniform scalar loads
    float* __restrict__ out,          // [0,B): real, [B,2B): imag
    int Bq)                            // B/4
{
    const int idx = blockIdx.x * blockDim.x + threadIdx.x;
    if (idx >= Bq) return;

    const float4 t4 = ((const float4*)th)[idx];   // 4 thetas, 16B coalesced

    float zs0, zc0, zs1, zc1, zs2, zc2, zs3, zc3;
    __sincosf(2.f * t4.x, &zs0, &zc0);
    __sincosf(2.f * t4.y, &zs1, &zc1);
    __sincosf(2.f * t4.z, &zs2, &zc2);
    __sincosf(2.f * t4.w, &zs3, &zc3);
    const v2f zrA = {zc0, zc1}, ziA = {zs0, zs1}, nziA = {-zs0, -zs1};
    const v2f zrB = {zc2, zc3}, ziB = {zs2, zs3}, nziB = {-zs2, -zs3};

    const float4 gt = tab[NPHI - 1];
    v2f arA = {gt.x, gt.y}, aiA = {gt.z, gt.w};
    v2f arB = {gt.x, gt.y}, aiB = {gt.z, gt.w};

    #pragma unroll 8
    for (int j = NPHI - 2; j >= 0; --j) {
        const float4 gj = tab[j];                 // uniform -> s_load_dwordx4
        const v2f gr = {gj.x, gj.y};
        const v2f gi = {gj.z, gj.w};
        const v2f nrA = __builtin_elementwise_fma(
            arA, zrA, __builtin_elementwise_fma(aiA, nziA, gr));
        const v2f niA = __builtin_elementwise_fma(
            arA, ziA, __builtin_elementwise_fma(aiA, zrA, gi));
        const v2f nrB = __builtin_elementwise_fma(
            arB, zrB, __builtin_elementwise_fma(aiB, nziB, gr));
        const v2f niB = __builtin_elementwise_fma(
            arB, ziB, __builtin_elementwise_fma(aiB, zrB, gi));
        arA = nrA; aiA = niA;
        arB = nrB; aiB = niB;
    }

    float S0, C0, S1, C1, S2, C2, S3, C3;
    __sincosf(127.f * t4.x, &S0, &C0);
    __sincosf(127.f * t4.y, &S1, &C1);
    __sincosf(127.f * t4.z, &S2, &C2);
    __sincosf(127.f * t4.w, &S3, &C3);
    const v2f CA = {C0, C1}, SA = {S0, S1};
    const v2f CB = {C2, C3}, SB = {S2, S3};
    const v2f orA = __builtin_elementwise_fma(arA, CA, aiA * SA);
    const v2f oiA = __builtin_elementwise_fma(aiA, CA, -(arA * SA));
    const v2f orB = __builtin_elementwise_fma(arB, CB, aiB * SB);
    const v2f oiB = __builtin_elementwise_fma(aiB, CB, -(arB * SB));

    ((float4*)out)[idx]      = make_float4(orA.x, orA.y, orB.x, orB.y);
    ((float4*)out)[idx + Bq] = make_float4(oiA.x, oiA.y, oiB.x, oiB.y);
}

extern "C" void kernel_launch(void* const* d_in, const int* in_sizes, int n_in,
                              void* d_out, int out_size, void* d_ws, size_t ws_size,
                              hipStream_t stream)
{
    const float* th   = (const float*)d_in[0];
    const float* phis = (const float*)d_in[1];
    float* out = (float*)d_out;
    float4* tab = (float4*)d_ws;        // 128 * 16 B = 2 KB scratch
    const int B = in_sizes[0];          // 2097152
    const int Bq = B >> 2;

    qsp_setup<<<1, 64, 0, stream>>>(phis, tab);

    const int block = 256;
    const int grid = (Bq + block - 1) / block;
    qsp_main<<<grid, block, 0, stream>>>(th, tab, out, Bq);
}

// Round 6
// 103.185 us; speedup vs baseline: 1.1215x; 1.1215x over previous
//
#include <hip/hip_runtime.h>

// QSP via Laurent polynomial, SINGLE fused kernel.
// u00(theta) = sum_{t=0..127} gamma_t e^{i(2t-127)theta}; gamma depends only on phis.
// Compressed coefficient recurrence (support after k steps is m=-k..k step 2;
// j=(m+k)/2 in [0,k]):
//   A'[j] = e_k  * 0.5*(A[j-1] + A[j] + B[j-1] - B[j])
//   B'[j] = ek^* * 0.5*(A[j-1] - A[j] + B[j-1] + B[j])
// Init A[0]=e_0. After k=127: gamma_t = A[t], t=0..127  (128 slots = 2/lane on 1 wave).
// Wave 0 of EVERY block computes gamma into LDS (registers + 4 shfl_up/iter, no
// barriers) while waves 1-3 do the theta/sincos prologue; then all waves Horner
// in z = e^{2 i theta} with broadcast LDS coefficient reads. 4 elems/thread.

typedef float v2f __attribute__((ext_vector_type(2)));

#define NPHI 128

__global__ __launch_bounds__(256, 8) void qsp_fused(
    const float* __restrict__ th,
    const float* __restrict__ phis,
    float* __restrict__ out,    // [0,B): real, [B,2B): imag
    int Bq)                      // B/4
{
    __shared__ float2 g2[NPHI];   // gamma_t = (re, im)
    __shared__ float2 e[NPHI];    // e^{i phi_k}

    const int tid = threadIdx.x;

    if (tid < 64) {
        const int L = tid;
        float sp, cp;
        __sincosf(phis[L], &sp, &cp);
        e[L] = make_float2(cp, sp);
        __sincosf(phis[L + 64], &sp, &cp);
        e[L + 64] = make_float2(cp, sp);
        // same-wave DS ordering: reads below see these writes (per-wave in-order DS)

        // lane L holds slots j=2L (s0), j=2L+1 (s1)
        float Ar0 = 0.f, Ai0 = 0.f, Br0 = 0.f, Bi0 = 0.f;
        float Ar1 = 0.f, Ai1 = 0.f, Br1 = 0.f, Bi1 = 0.f;
        const float2 e0 = e[0];
        if (L == 0) { Ar0 = e0.x; Ai0 = e0.y; }   // k=0: A[0]=e_0

        for (int k = 1; k < NPHI; ++k) {
            const float2 ek = e[k];
            // prev slot j-1 for s0 lives in lane L-1's s1
            float pAr = __shfl_up(Ar1, 1, 64);
            float pAi = __shfl_up(Ai1, 1, 64);
            float pBr = __shfl_up(Br1, 1, 64);
            float pBi = __shfl_up(Bi1, 1, 64);
            if (L == 0) { pAr = 0.f; pAi = 0.f; pBr = 0.f; pBi = 0.f; }
            // slot0: Am=p (j-1), Ap=s0 (j)
            const float s0Ar = 0.5f * (pAr + Ar0 + pBr - Br0);
            const float s0Ai = 0.5f * (pAi + Ai0 + pBi - Bi0);
            const float s0Br = 0.5f * (pAr - Ar0 + pBr + Br0);
            const float s0Bi = 0.5f * (pAi - Ai0 + pBi + Bi0);
            // slot1: Am=s0 (j-1=2L), Ap=s1 (j=2L+1)
            const float s1Ar = 0.5f * (Ar0 + Ar1 + Br0 - Br1);
            const float s1Ai = 0.5f * (Ai0 + Ai1 + Bi0 - Bi1);
            const float s1Br = 0.5f * (Ar0 - Ar1 + Br0 + Br1);
            const float s1Bi = 0.5f * (Ai0 - Ai1 + Bi0 + Bi1);
            Ar0 = ek.x * s0Ar - ek.y * s0Ai;  Ai0 = ek.x * s0Ai + ek.y * s0Ar;
            Br0 = ek.x * s0Br + ek.y * s0Bi;  Bi0 = ek.x * s0Bi - ek.y * s0Br;
            Ar1 = ek.x * s1Ar - ek.y * s1Ai;  Ai1 = ek.x * s1Ai + ek.y * s1Ar;
            Br1 = ek.x * s1Br + ek.y * s1Bi;  Bi1 = ek.x * s1Bi - ek.y * s1Br;
        }
        g2[2 * L]     = make_float2(Ar0, Ai0);
        g2[2 * L + 1] = make_float2(Ar1, Ai1);
    }

    // ---- prologue: independent of gamma, runs while wave 0 computes setup ----
    const int idx = blockIdx.x * blockDim.x + tid;
    const int lidx = (idx < Bq) ? idx : 0;
    const float4 t4 = ((const float4*)th)[lidx];

    float zs0, zc0, zs1, zc1, zs2, zc2, zs3, zc3;
    __sincosf(2.f * t4.x, &zs0, &zc0);
    __sincosf(2.f * t4.y, &zs1, &zc1);
    __sincosf(2.f * t4.z, &zs2, &zc2);
    __sincosf(2.f * t4.w, &zs3, &zc3);
    const v2f zrA = {zc0, zc1}, ziA = {zs0, zs1}, nziA = {-zs0, -zs1};
    const v2f zrB = {zc2, zc3}, ziB = {zs2, zs3}, nziB = {-zs2, -zs3};

    float S0, C0, S1, C1, S2, C2, S3, C3;
    __sincosf(127.f * t4.x, &S0, &C0);
    __sincosf(127.f * t4.y, &S1, &C1);
    __sincosf(127.f * t4.z, &S2, &C2);
    __sincosf(127.f * t4.w, &S3, &C3);

    __syncthreads();

    // ---- Horner in z = e^{2 i theta} ----
    const float2 gt = g2[NPHI - 1];
    v2f arA = {gt.x, gt.x}, aiA = {gt.y, gt.y};
    v2f arB = arA,          aiB = aiA;

    #pragma unroll 4
    for (int j = NPHI - 2; j >= 0; --j) {
        const float2 gj = g2[j];          // ds_read_b64, broadcast
        const v2f gr = {gj.x, gj.x};      // op_sel splat
        const v2f gi = {gj.y, gj.y};
        const v2f nrA = __builtin_elementwise_fma(
            arA, zrA, __builtin_elementwise_fma(aiA, nziA, gr));
        const v2f niA = __builtin_elementwise_fma(
            arA, ziA, __builtin_elementwise_fma(aiA, zrA, gi));
        const v2f nrB = __builtin_elementwise_fma(
            arB, zrB, __builtin_elementwise_fma(aiB, nziB, gr));
        const v2f niB = __builtin_elementwise_fma(
            arB, ziB, __builtin_elementwise_fma(aiB, zrB, gi));
        arA = nrA; aiA = niA;
        arB = nrB; aiB = niB;
    }

    // multiply by e^{-127 i theta}
    const v2f CA = {C0, C1}, SA = {S0, S1};
    const v2f CB = {C2, C3}, SB = {S2, S3};
    const v2f orA = __builtin_elementwise_fma(arA, CA, aiA * SA);
    const v2f oiA = __builtin_elementwise_fma(aiA, CA, -(arA * SA));
    const v2f orB = __builtin_elementwise_fma(arB, CB, aiB * SB);
    const v2f oiB = __builtin_elementwise_fma(aiB, CB, -(arB * SB));

    if (idx < Bq) {
        ((float4*)out)[idx]      = make_float4(orA.x, orA.y, orB.x, orB.y);
        ((float4*)out)[idx + Bq] = make_float4(oiA.x, oiA.y, oiB.x, oiB.y);
    }
}

extern "C" void kernel_launch(void* const* d_in, const int* in_sizes, int n_in,
                              void* d_out, int out_size, void* d_ws, size_t ws_size,
                              hipStream_t stream)
{
    const float* th   = (const float*)d_in[0];
    const float* phis = (const float*)d_in[1];
    float* out = (float*)d_out;
    const int B = in_sizes[0];          // 2097152
    const int Bq = B >> 2;              // 524288 threads
    const int block = 256;
    const int grid = (Bq + block - 1) / block;   // 2048 blocks = exactly resident
    qsp_fused<<<grid, block, 0, stream>>>(th, phis, out, Bq);
}

// Round 7
// 89.913 us; speedup vs baseline: 1.2870x; 1.1476x over previous
//
#include <hip/hip_runtime.h>

// QSP via Laurent polynomial, single fused kernel.
// u00(theta) = sum_{t=0..127} gamma_t e^{i(2t-127)theta}; gamma depends only on phis.
// Compressed recurrence (j=(m+k)/2 in [0,k], validated R6):
//   A'[j] = e_k  * 0.5*(A[j-1] + A[j] + B[j-1] - B[j])
//   B'[j] = ek^* * 0.5*(A[j-1] - A[j] + B[j-1] + B[j])
// R7: block=1024 (16 waves, 2 blocks/CU -> only 512 redundant setup waves);
// setup fully packed v2f: butterfly sums (u+v/u-v) + VOP3P complex rotations with
// 0.5 folded into h_k = 0.5 e^{i phi_k}. Wave 0 computes gamma -> LDS; all waves
// then Horner in z = e^{2 i theta}, 4 elems/thread, broadcast LDS coeff reads.

typedef float v2f __attribute__((ext_vector_type(2)));

#define NPHI 128

__global__ __launch_bounds__(1024, 8) void qsp_fused(
    const float* __restrict__ th,
    const float* __restrict__ phis,
    float* __restrict__ out,    // [0,B): real, [B,2B): imag
    int Bq)                      // B/4
{
    __shared__ float2 g2[NPHI];   // gamma_t = (re, im)
    __shared__ float2 h[NPHI];    // 0.5 * e^{i phi_k}

    const int tid = threadIdx.x;

    if (tid < 64) {
        const int L = tid;
        float sp, cp;
        __sincosf(phis[L], &sp, &cp);
        h[L] = make_float2(0.5f * cp, 0.5f * sp);
        __sincosf(phis[L + 64], &sp, &cp);
        h[L + 64] = make_float2(0.5f * cp, 0.5f * sp);
        // same-wave DS ordering: reads below see these writes

        // lane L holds slots j=2L (A0/B0), j=2L+1 (A1/B1); (re,im) packed in v2f
        v2f A0 = {0.f, 0.f}, B0 = {0.f, 0.f};
        v2f A1 = {0.f, 0.f}, B1 = {0.f, 0.f};
        const float2 h0 = h[0];
        if (L == 0) A0 = (v2f){2.f * h0.x, 2.f * h0.y};   // A[0] = e_0

        #pragma unroll 4
        for (int k = 1; k < NPHI; ++k) {
            const float2 hk = h[k];          // broadcast, prefetchable
            const v2f hx  = {hk.x, hk.x};
            const v2f hyn = {-hk.y, hk.y};   // e_k ⊛ t
            const v2f hyp = {hk.y, -hk.y};   // conj(e_k) ⊛ t
            // neighbor j-1 for slot0 = lane L-1's slot1
            const float pAr = __shfl_up(A1.x, 1, 64);
            const float pAi = __shfl_up(A1.y, 1, 64);
            const float pBr = __shfl_up(B1.x, 1, 64);
            const float pBi = __shfl_up(B1.y, 1, 64);
            v2f pA = {pAr, pAi}, pB = {pBr, pBi};
            if (L == 0) { pA = (v2f){0.f, 0.f}; pB = (v2f){0.f, 0.f}; }
            // butterfly sums (2x the R6 s-values; 0.5 folded into h)
            const v2f u0 = pA + pB, v0 = A0 - B0;
            const v2f sA0 = u0 + v0, sB0 = u0 - v0;
            const v2f u1 = A0 + B0, v1 = A1 - B1;
            const v2f sA1 = u1 + v1, sB1 = u1 - v1;
            // rotations: h ⊛ t = hx*t + {-hy,hy}*swap(t); conj uses {hy,-hy}
            v2f ts;
            ts = (v2f){sA0.y, sA0.x};
            A0 = __builtin_elementwise_fma(hyn, ts, hx * sA0);
            ts = (v2f){sB0.y, sB0.x};
            B0 = __builtin_elementwise_fma(hyp, ts, hx * sB0);
            ts = (v2f){sA1.y, sA1.x};
            A1 = __builtin_elementwise_fma(hyn, ts, hx * sA1);
            ts = (v2f){sB1.y, sB1.x};
            B1 = __builtin_elementwise_fma(hyp, ts, hx * sB1);
        }
        g2[2 * L]     = make_float2(A0.x, A0.y);   // gamma_{2L}
        g2[2 * L + 1] = make_float2(A1.x, A1.y);   // gamma_{2L+1}
    }

    // ---- prologue: gamma-independent, overlaps wave 0's setup ----
    const int idx = blockIdx.x * blockDim.x + tid;
    const int lidx = (idx < Bq) ? idx : 0;
    const float4 t4 = ((const float4*)th)[lidx];

    float zs0, zc0, zs1, zc1, zs2, zc2, zs3, zc3;
    __sincosf(2.f * t4.x, &zs0, &zc0);
    __sincosf(2.f * t4.y, &zs1, &zc1);
    __sincosf(2.f * t4.z, &zs2, &zc2);
    __sincosf(2.f * t4.w, &zs3, &zc3);
    const v2f zrA = {zc0, zc1}, ziA = {zs0, zs1}, nziA = {-zs0, -zs1};
    const v2f zrB = {zc2, zc3}, ziB = {zs2, zs3}, nziB = {-zs2, -zs3};

    float S0, C0, S1, C1, S2, C2, S3, C3;
    __sincosf(127.f * t4.x, &S0, &C0);
    __sincosf(127.f * t4.y, &S1, &C1);
    __sincosf(127.f * t4.z, &S2, &C2);
    __sincosf(127.f * t4.w, &S3, &C3);

    __syncthreads();

    // ---- Horner in z = e^{2 i theta} ----
    const float2 gt = g2[NPHI - 1];
    v2f arA = {gt.x, gt.x}, aiA = {gt.y, gt.y};
    v2f arB = arA,          aiB = aiA;

    #pragma unroll 4
    for (int j = NPHI - 2; j >= 0; --j) {
        const float2 gj = g2[j];          // ds_read_b64, broadcast
        const v2f gr = {gj.x, gj.x};
        const v2f gi = {gj.y, gj.y};
        const v2f nrA = __builtin_elementwise_fma(
            arA, zrA, __builtin_elementwise_fma(aiA, nziA, gr));
        const v2f niA = __builtin_elementwise_fma(
            arA, ziA, __builtin_elementwise_fma(aiA, zrA, gi));
        const v2f nrB = __builtin_elementwise_fma(
            arB, zrB, __builtin_elementwise_fma(aiB, nziB, gr));
        const v2f niB = __builtin_elementwise_fma(
            arB, ziB, __builtin_elementwise_fma(aiB, zrB, gi));
        arA = nrA; aiA = niA;
        arB = nrB; aiB = niB;
    }

    // multiply by e^{-127 i theta}
    const v2f CA = {C0, C1}, SA = {S0, S1};
    const v2f CB = {C2, C3}, SB = {S2, S3};
    const v2f orA = __builtin_elementwise_fma(arA, CA, aiA * SA);
    const v2f oiA = __builtin_elementwise_fma(aiA, CA, -(arA * SA));
    const v2f orB = __builtin_elementwise_fma(arB, CB, aiB * SB);
    const v2f oiB = __builtin_elementwise_fma(aiB, CB, -(arB * SB));

    if (idx < Bq) {
        ((float4*)out)[idx]      = make_float4(orA.x, orA.y, orB.x, orB.y);
        ((float4*)out)[idx + Bq] = make_float4(oiA.x, oiA.y, oiB.x, oiB.y);
    }
}

extern "C" void kernel_launch(void* const* d_in, const int* in_sizes, int n_in,
                              void* d_out, int out_size, void* d_ws, size_t ws_size,
                              hipStream_t stream)
{
    const float* th   = (const float*)d_in[0];
    const float* phis = (const float*)d_in[1];
    float* out = (float*)d_out;
    const int B = in_sizes[0];          // 2097152
    const int Bq = B >> 2;              // 524288 threads
    const int block = 1024;             // 16 waves; 2 blocks/CU
    const int grid = (Bq + block - 1) / block;   // 512 blocks
    qsp_fused<<<grid, block, 0, stream>>>(th, phis, out, Bq);
}

// Round 8
// 88.115 us; speedup vs baseline: 1.3133x; 1.0204x over previous
//
#include <hip/hip_runtime.h>

// QSP via Laurent polynomial, single fused kernel.
// u00(theta) = sum_{t=0..127} gamma_t e^{i(2t-127)theta}; gamma depends only on phis.
// Compressed recurrence (j=(m+k)/2 in [0,k], validated R6/R7):
//   A'[j] = e_k  * 0.5*(A[j-1] + A[j] + B[j-1] - B[j])
//   B'[j] = ek^* * 0.5*(A[j-1] - A[j] + B[j-1] + B[j])
// R8: setup cross-lane hop via DPP wave_shr:1 (VALU latency, not ds_bpermute's
// ~120cyc; bound_ctrl zeroes lane 0) -> serial setup window ~2us. Horner does
// 8 elements/thread with ds_read_b128 coefficient reads (2 gammas/read) ->
// DS pipe halved and hidden under packed-FMA VALU. block=512, grid=512.

typedef float v2f __attribute__((ext_vector_type(2)));

#define NPHI 128

__device__ __forceinline__ float wave_shr1(float x) {
    // lane L <- lane L-1, lane 0 <- 0 (DPP wave_shr:1, bound_ctrl=1)
    return __builtin_bit_cast(float,
        __builtin_amdgcn_update_dpp(0, __builtin_bit_cast(int, x),
                                    0x138, 0xf, 0xf, true));
}

__global__ __launch_bounds__(512, 4) void qsp_fused(
    const float* __restrict__ th,
    const float* __restrict__ phis,
    float* __restrict__ out,    // [0,B): real, [B,2B): imag
    int Bq8)                     // B/8
{
    __shared__ alignas(16) float2 g2[NPHI];   // gamma_t
    __shared__ float2 h[NPHI];                // 0.5 * e^{i phi_k}

    const int tid = threadIdx.x;

    if (tid < 64) {
        const int L = tid;
        float sp, cp;
        __sincosf(phis[L], &sp, &cp);
        h[L] = make_float2(0.5f * cp, 0.5f * sp);
        __sincosf(phis[L + 64], &sp, &cp);
        h[L + 64] = make_float2(0.5f * cp, 0.5f * sp);
        // same-wave DS ordering: reads below see these writes

        // lane L holds slots j=2L, j=2L+1; (re,im) packed in v2f
        v2f A0 = {0.f, 0.f}, B0 = {0.f, 0.f};
        v2f A1 = {0.f, 0.f}, B1 = {0.f, 0.f};
        const float2 h0 = h[0];
        if (L == 0) A0 = (v2f){2.f * h0.x, 2.f * h0.y};   // A[0] = e_0

        #pragma unroll 4
        for (int k = 1; k < NPHI; ++k) {
            const float2 hk = h[k];          // broadcast, off critical path
            const v2f hx  = {hk.x, hk.x};
            const v2f hyn = {-hk.y, hk.y};   // e_k ⊛ t
            const v2f hyp = {hk.y, -hk.y};   // conj(e_k) ⊛ t
            // neighbor j-1 for slot0 = lane L-1's slot1 (DPP, lane0 -> 0)
            const v2f pA = { wave_shr1(A1.x), wave_shr1(A1.y) };
            const v2f pB = { wave_shr1(B1.x), wave_shr1(B1.y) };
            const v2f u0 = pA + pB, v0 = A0 - B0;
            const v2f sA0 = u0 + v0, sB0 = u0 - v0;
            const v2f u1 = A0 + B0, v1 = A1 - B1;
            const v2f sA1 = u1 + v1, sB1 = u1 - v1;
            v2f ts;
            ts = (v2f){sA0.y, sA0.x};
            A0 = __builtin_elementwise_fma(hyn, ts, hx * sA0);
            ts = (v2f){sB0.y, sB0.x};
            B0 = __builtin_elementwise_fma(hyp, ts, hx * sB0);
            ts = (v2f){sA1.y, sA1.x};
            A1 = __builtin_elementwise_fma(hyn, ts, hx * sA1);
            ts = (v2f){sB1.y, sB1.x};
            B1 = __builtin_elementwise_fma(hyp, ts, hx * sB1);
        }
        g2[2 * L]     = make_float2(A0.x, A0.y);   // gamma_{2L}
        g2[2 * L + 1] = make_float2(A1.x, A1.y);   // gamma_{2L+1}
    }

    // ---- prologue: gamma-independent, overlaps wave 0's setup ----
    const int idx = blockIdx.x * blockDim.x + tid;
    const int lidx = (idx < Bq8) ? idx : 0;
    const float4 ta = ((const float4*)th)[2 * lidx];
    const float4 tb = ((const float4*)th)[2 * lidx + 1];
    const float th8[8] = {ta.x, ta.y, ta.z, ta.w, tb.x, tb.y, tb.z, tb.w};

    v2f zr[4], zi[4], nzi[4], Cc[4], Ss[4];
    #pragma unroll
    for (int g = 0; g < 4; ++g) {
        float s0, c0, s1, c1;
        __sincosf(2.f * th8[2 * g],     &s0, &c0);
        __sincosf(2.f * th8[2 * g + 1], &s1, &c1);
        zr[g]  = (v2f){c0, c1};
        zi[g]  = (v2f){s0, s1};
        nzi[g] = (v2f){-s0, -s1};
        __sincosf(127.f * th8[2 * g],     &s0, &c0);
        __sincosf(127.f * th8[2 * g + 1], &s1, &c1);
        Cc[g] = (v2f){c0, c1};
        Ss[g] = (v2f){s0, s1};
    }

    __syncthreads();

    // ---- Horner in z = e^{2 i theta}, 128 steps (t=127..0), acc starts 0 ----
    v2f ar[4] = {{0.f,0.f},{0.f,0.f},{0.f,0.f},{0.f,0.f}};
    v2f ai[4] = {{0.f,0.f},{0.f,0.f},{0.f,0.f},{0.f,0.f}};
    const float4* g4 = (const float4*)g2;

    #pragma unroll 4
    for (int jj = NPHI / 2 - 1; jj >= 0; --jj) {
        const float4 gp = g4[jj];   // {g_{2jj}.re, .im, g_{2jj+1}.re, .im}
        {   // t = 2jj+1
            const v2f gr = {gp.z, gp.z}, gi = {gp.w, gp.w};
            #pragma unroll
            for (int g = 0; g < 4; ++g) {
                const v2f nr = __builtin_elementwise_fma(
                    ar[g], zr[g], __builtin_elementwise_fma(ai[g], nzi[g], gr));
                const v2f ni = __builtin_elementwise_fma(
                    ar[g], zi[g], __builtin_elementwise_fma(ai[g], zr[g], gi));
                ar[g] = nr; ai[g] = ni;
            }
        }
        {   // t = 2jj
            const v2f gr = {gp.x, gp.x}, gi = {gp.y, gp.y};
            #pragma unroll
            for (int g = 0; g < 4; ++g) {
                const v2f nr = __builtin_elementwise_fma(
                    ar[g], zr[g], __builtin_elementwise_fma(ai[g], nzi[g], gr));
                const v2f ni = __builtin_elementwise_fma(
                    ar[g], zi[g], __builtin_elementwise_fma(ai[g], zr[g], gi));
                ar[g] = nr; ai[g] = ni;
            }
        }
    }

    // ---- multiply by e^{-127 i theta}, store ----
    v2f orv[4], oiv[4];
    #pragma unroll
    for (int g = 0; g < 4; ++g) {
        orv[g] = __builtin_elementwise_fma(ar[g], Cc[g], ai[g] * Ss[g]);
        oiv[g] = __builtin_elementwise_fma(ai[g], Cc[g], -(ar[g] * Ss[g]));
    }

    if (idx < Bq8) {
        float4* o4 = (float4*)out;
        const int ib = 2 * Bq8;   // imag base in float4 units (= B/4)
        o4[2 * idx]          = make_float4(orv[0].x, orv[0].y, orv[1].x, orv[1].y);
        o4[2 * idx + 1]      = make_float4(orv[2].x, orv[2].y, orv[3].x, orv[3].y);
        o4[ib + 2 * idx]     = make_float4(oiv[0].x, oiv[0].y, oiv[1].x, oiv[1].y);
        o4[ib + 2 * idx + 1] = make_float4(oiv[2].x, oiv[2].y, oiv[3].x, oiv[3].y);
    }
}

extern "C" void kernel_launch(void* const* d_in, const int* in_sizes, int n_in,
                              void* d_out, int out_size, void* d_ws, size_t ws_size,
                              hipStream_t stream)
{
    const float* th   = (const float*)d_in[0];
    const float* phis = (const float*)d_in[1];
    float* out = (float*)d_out;
    const int B = in_sizes[0];          // 2097152
    const int Bq8 = B >> 3;             // 262144 threads
    const int block = 512;              // 8 waves; 2 blocks/CU
    const int grid = (Bq8 + block - 1) / block;   // 512 blocks
    qsp_fused<<<grid, block, 0, stream>>>(th, phis, out, Bq8);
}